// Round 8
// baseline (336.090 us; speedup 1.0000x reference)
//
#include <hip/hip_runtime.h>
#include <math.h>

#define NF 8
#define NQ 300
#define HSZ 96
#define WSZ 96
#define HW (HSZ*WSZ)        // 9216
#define DTOT (NF*HW)        // 73728
#define NBF 16              // bs*NF

// ws layout (float indices)
#define WS_TGTY  0           // [16][96]  max over h, indexed [bf][w]
#define WS_TGTX  1536        // [16][96]  max over w, indexed [bf][h]
#define WS_TSUM  3072        // [16]
#define WS_YSUM  3088        // [16]
#define WS_XSUM  3104        // [16]
#define WS_TBITS 3136        // [16][288] uint bitmask of tmask!=0 (LSB-first per 32 elems)
#define WS_PBITS 7744        // [2][288]  uint bitmask of vpad!=0
#define WS_PART  8320        // [2][300][8][8] partials, contiguous per (b,q)

typedef float f32x4 __attribute__((ext_vector_type(4)));

__device__ __forceinline__ float sigmoid_fast(float x) {
    float e = __expf(-fabsf(x));
    float inv = __builtin_amdgcn_rcpf(1.f + e);
    return x >= 0.f ? inv : e * inv;
}

// forced (unsinkable) global load: 16B dwordx4 via inline asm
__device__ __forceinline__ f32x4 gload4(const f32x4* p) {
    f32x4 d;
    asm volatile("global_load_dwordx4 %0, %1, off" : "=v"(d) : "v"(p));
    return d;
}

#define WAITV(N) do { \
    asm volatile("s_waitcnt vmcnt(" #N ")" ::: "memory"); \
    __builtin_amdgcn_sched_barrier(0); \
} while (0)

// ---------------------------------------------------------------------------
// targets_kernel: one block (1024 thr) per (b,f).
// ---------------------------------------------------------------------------
#define NTT 1024
__global__ __launch_bounds__(NTT)
void targets_kernel(const float* __restrict__ tm, const unsigned char* __restrict__ vpad,
                    float* __restrict__ ws) {
    int bf = blockIdx.x, t = threadIdx.x;
    int lane = t & 63, wid = t >> 6;
    __shared__ float tile[HSZ * 97];
    __shared__ float redt[16 * 3];
    const float* base = tm + (size_t)bf * HW;
    unsigned* tbw = (unsigned*)(ws + WS_TBITS) + bf * 288;

    float tsum = 0.f;
    #pragma unroll
    for (int it = 0; it < 9; ++it) {
        int e = it * NTT + t;
        float v = base[e];
        tsum += v;
        tile[e + e / 96] = v;                       // stride-97 padded
        unsigned long long m = __ballot(v != 0.f);
        int word = it * 32 + wid * 2;
        if (lane == 0)       tbw[word]     = (unsigned)m;
        else if (lane == 32) tbw[word + 1] = (unsigned)(m >> 32);
    }
    if ((bf & 7) == 0) {                            // pack vpad for this b
        const unsigned char* vb = vpad + (size_t)(bf >> 3) * HW;
        unsigned* pbw = (unsigned*)(ws + WS_PBITS) + (bf >> 3) * 288;
        #pragma unroll
        for (int it = 0; it < 9; ++it) {
            int e = it * NTT + t;
            unsigned long long m = __ballot(vb[e] != 0);
            int word = it * 32 + wid * 2;
            if (lane == 0)       pbw[word]     = (unsigned)m;
            else if (lane == 32) pbw[word + 1] = (unsigned)(m >> 32);
        }
    }
    __syncthreads();

    float ysum = 0.f, xsum = 0.f;
    if (t < 96) {
        float m = -INFINITY;
        #pragma unroll 8
        for (int h = 0; h < HSZ; ++h) m = fmaxf(m, tile[h * 97 + t]);
        ws[WS_TGTY + bf * 96 + t] = m;
        ysum = m;
    } else if (t < 192) {
        int hh = t - 96;
        float m = -INFINITY;
        #pragma unroll 8
        for (int w = 0; w < WSZ; ++w) m = fmaxf(m, tile[hh * 97 + w]);
        ws[WS_TGTX + bf * 96 + hh] = m;
        xsum = m;
    }
    float s0 = tsum, s1 = ysum, s2 = xsum;
    #pragma unroll
    for (int off = 32; off > 0; off >>= 1) {
        s0 += __shfl_down(s0, off, 64);
        s1 += __shfl_down(s1, off, 64);
        s2 += __shfl_down(s2, off, 64);
    }
    if (lane == 0) { redt[wid * 3] = s0; redt[wid * 3 + 1] = s1; redt[wid * 3 + 2] = s2; }
    __syncthreads();
    if (t == 0) {
        float a0 = 0.f, a1 = 0.f, a2 = 0.f;
        #pragma unroll
        for (int w = 0; w < 16; ++w) {
            a0 += redt[w * 3]; a1 += redt[w * 3 + 1]; a2 += redt[w * 3 + 2];
        }
        ws[WS_TSUM + bf] = a0;
        ws[WS_YSUM + bf] = a1;
        ws[WS_XSUM + bf] = a2;
    }
}

// ---------------------------------------------------------------------------
// partial_kernel: one block (384 thr = 16x24) per (b,f, 3 consecutive q).
// Rolling inline-asm prefetch: plane p+1's 6 global_load_dwordx4 are issued
// (asm volatile - unsinkable) before plane p's compute; counted vmcnt(6)
// keeps them in flight across the compute + raw barriers. Compiler loads
// (tw/pw/gy/gx) are force-materialized BEFORE any asm VMEM so the compiler's
// own waitcnt bookkeeping cannot drain the prefetch.
// ---------------------------------------------------------------------------
#define NTP 384
#define QPB 3
#define NPLB (NQ/QPB)        // 100

// per-element focal/dice math (softplus identity; |x| small -> e^x safe)
#define EL(X, TB) do { \
    float x_ = (X); float tg_ = (float)(TB); \
    float e2_ = __expf(x_); \
    float se_ = 1.f + e2_; \
    float inv_ = __builtin_amdgcn_rcpf(se_); \
    float s_ = e2_ * inv_; \
    float L_ = __logf(se_); \
    float ce_ = fmaf(-x_, tg_, L_); \
    float omp_ = fmaf(tg_, fmaf(-2.f, s_, 1.f), s_); \
    float at_ = fmaf(tg_, -0.5f, 0.75f); \
    focal = fmaf(at_ * ce_, omp_ * omp_, focal); \
    dnum = fmaf(s_, tg_, dnum); \
    dden += s_; \
    rmx = fmaxf(rmx, x_); \
} while (0)

#define KSTEP(KK, XV) do { \
    unsigned tn_ = (tw[KK] >> wsh) & 0xFu; \
    unsigned pn_ = (pw[KK] >> wsh) & 0xFu; \
    float xs0 = (XV).x, xs1 = (XV).y, xs2 = (XV).z, xs3 = (XV).w; \
    if (pn_) { \
        if (pn_ & 1u) xs0 = 0.f; \
        if (pn_ & 2u) xs1 = 0.f; \
        if (pn_ & 4u) xs2 = 0.f; \
        if (pn_ & 8u) xs3 = 0.f; \
    } \
    float rmx = -INFINITY; \
    EL(xs0, tn_ & 1u); EL(xs1, (tn_ >> 1) & 1u); \
    EL(xs2, (tn_ >> 2) & 1u); EL(xs3, (tn_ >> 3) & 1u); \
    cm0 = fmaxf(cm0, xs0); cm1 = fmaxf(cm1, xs1); \
    cm2 = fmaxf(cm2, xs2); cm3 = fmaxf(cm3, xs3); \
    rp[(16 * (KK) + r0) * 25 + w4] = rmx; \
} while (0)

#define PLANE(X0,X1,X2,X3,X4,X5, QI) do { \
    float focal = 0.f, dnum = 0.f, dden = 0.f; \
    float cm0 = -INFINITY, cm1 = -INFINITY, cm2 = -INFINITY, cm3 = -INFINITY; \
    KSTEP(0, X0); KSTEP(1, X1); KSTEP(2, X2); \
    KSTEP(3, X3); KSTEP(4, X4); KSTEP(5, X5); \
    { f32x4 cmv_ = {cm0, cm1, cm2, cm3}; *(f32x4*)&cp[r0 * 100 + w4 * 4] = cmv_; } \
    asm volatile("s_waitcnt lgkmcnt(0)" ::: "memory"); \
    __builtin_amdgcn_s_barrier(); \
    __builtin_amdgcn_sched_barrier(0); \
    float v0 = focal, v1 = dnum, v2 = dden, v3 = 0.f, v4 = 0.f, v5 = 0.f, v6 = 0.f; \
    if (t < 96) { \
        float m_ = -INFINITY; \
        _Pragma("unroll") \
        for (int p_ = 0; p_ < 16; ++p_) m_ = fmaxf(m_, cp[p_ * 100 + t]); \
        float sg_ = sigmoid_fast(m_); \
        v4 = sg_; v3 = sg_ * gy; \
    } else if (t < 192) { \
        int r_ = t - 96; \
        float m_ = rp[r_ * 25]; \
        _Pragma("unroll") \
        for (int c_ = 1; c_ < 24; ++c_) m_ = fmaxf(m_, rp[r_ * 25 + c_]); \
        float sg_ = sigmoid_fast(m_); \
        v6 = sg_; v5 = sg_ * gx; \
    } \
    _Pragma("unroll") \
    for (int off_ = 32; off_ > 0; off_ >>= 1) { \
        v0 += __shfl_down(v0, off_, 64); \
        v1 += __shfl_down(v1, off_, 64); \
        v2 += __shfl_down(v2, off_, 64); \
        v3 += __shfl_down(v3, off_, 64); \
        v4 += __shfl_down(v4, off_, 64); \
        v5 += __shfl_down(v5, off_, 64); \
        v6 += __shfl_down(v6, off_, 64); \
    } \
    if ((t & 63) == 0) { \
        int wid_ = t >> 6; \
        red[wid_][0] = v0; red[wid_][1] = v1; red[wid_][2] = v2; red[wid_][3] = v3; \
        red[wid_][4] = v4; red[wid_][5] = v5; red[wid_][6] = v6; \
    } \
    asm volatile("s_waitcnt lgkmcnt(0)" ::: "memory"); \
    __builtin_amdgcn_s_barrier(); \
    __builtin_amdgcn_sched_barrier(0); \
    if (t < 7) { \
        float tot_ = red[0][t] + red[1][t] + red[2][t] + red[3][t] + red[4][t] + red[5][t]; \
        part[(size_t)((b * NQ + (QI)) * NF + f) * 8 + t] = tot_; \
    } \
} while (0)

__global__ __launch_bounds__(NTP, 4)
void partial_kernel(const float* __restrict__ masks, const float* __restrict__ ws,
                    float* __restrict__ part) {
    int bid = blockIdx.x;
    int bf  = bid / NPLB;
    int q0  = (bid - bf * NPLB) * QPB;
    int b   = bf >> 3, f = bf & 7;
    int t   = threadIdx.x;
    int w4  = t % 24;                // fixed float4-column group
    int r0  = t / 24;                // 0..15
    int wsh = (t & 7) * 4;           // nibble shift within bit-word

    __shared__ float rp[96 * 25];    // row-max partials [h][w4], +1 pad
    __shared__ float cp[16 * 100];   // col-max partials [r0][w], +4 pad
    __shared__ float red[6][8];

    const unsigned* tbw = (const unsigned*)(ws + WS_TBITS) + bf * 288;
    const unsigned* pbw = (const unsigned*)(ws + WS_PBITS) + b * 288;

    // ---- q-invariant state (compiler loads) ----
    unsigned tw[6], pw[6];
    #pragma unroll
    for (int k = 0; k < 6; ++k) tw[k] = tbw[k * 48 + (t >> 3)];
    #pragma unroll
    for (int k = 0; k < 6; ++k) pw[k] = pbw[k * 48 + (t >> 3)];
    float gy = 0.f, gx = 0.f;
    if (t < 96)       gy = ws[WS_TGTY + bf * 96 + t];
    else if (t < 192) gx = ws[WS_TGTX + bf * 96 + (t - 96)];

    // Force materialization: compiler emits its own waitcnts HERE, before any
    // asm VMEM below, so its (asm-blind) vmcnt bookkeeping can't drain our
    // prefetch later.
    #pragma unroll
    for (int k = 0; k < 6; ++k) {
        asm volatile("" : "+v"(tw[k]));
        asm volatile("" : "+v"(pw[k]));
    }
    asm volatile("" : "+v"(gy), "+v"(gx));

    const f32x4* base = (const f32x4*)(masks + (size_t)(bf * NQ + q0) * HW);

    // ---- rolling prefetch over 3 planes ----
    f32x4 a0, a1, a2, a3, a4, a5, b0, b1, b2, b3, b4, b5;
    a0 = gload4(base + 0 * NTP + t);           // plane 0
    a1 = gload4(base + 1 * NTP + t);
    a2 = gload4(base + 2 * NTP + t);
    a3 = gload4(base + 3 * NTP + t);
    a4 = gload4(base + 4 * NTP + t);
    a5 = gload4(base + 5 * NTP + t);
    b0 = gload4(base + 2304 + 0 * NTP + t);    // plane 1
    b1 = gload4(base + 2304 + 1 * NTP + t);
    b2 = gload4(base + 2304 + 2 * NTP + t);
    b3 = gload4(base + 2304 + 3 * NTP + t);
    b4 = gload4(base + 2304 + 4 * NTP + t);
    b5 = gload4(base + 2304 + 5 * NTP + t);

    WAITV(6);                                  // plane 0 ready; plane 1 in flight
    PLANE(a0, a1, a2, a3, a4, a5, q0);

    a0 = gload4(base + 4608 + 0 * NTP + t);    // plane 2 into dead a-regs
    a1 = gload4(base + 4608 + 1 * NTP + t);
    a2 = gload4(base + 4608 + 2 * NTP + t);
    a3 = gload4(base + 4608 + 3 * NTP + t);
    a4 = gload4(base + 4608 + 4 * NTP + t);
    a5 = gload4(base + 4608 + 5 * NTP + t);

    WAITV(6);                                  // plane 1 ready; plane 2 in flight
    PLANE(b0, b1, b2, b3, b4, b5, q0 + 1);

    WAITV(0);                                  // plane 2 ready
    PLANE(a0, a1, a2, a3, a4, a5, q0 + 2);
}

// ---------------------------------------------------------------------------
// combine+argmin fused: single block, 640 threads.
// ---------------------------------------------------------------------------
#define NTF 640
__global__ __launch_bounds__(NTF)
void combine_argmin_kernel(const float* __restrict__ logits, const float* __restrict__ boxes,
                           const float* __restrict__ tbox, const int* __restrict__ tvalid,
                           const float* __restrict__ ws, float* __restrict__ out,
                           int write_idx) {
    int t = threadIdx.x;
    __shared__ float sv[2 * NQ];

    if (t < 2 * NQ) {
        int b = t / NQ, q = t - b * NQ;

        const float* pbase = ws + WS_PART + (size_t)t * (NF * 8);
        float focal = 0.f, dnum = 0.f, dden = 0.f;
        float pYn = 0.f, pYd = 0.f, pXn = 0.f, pXd = 0.f;
        float tsum = 0.f, ysum = 0.f, xsum = 0.f;
        #pragma unroll
        for (int f = 0; f < NF; ++f) {
            int bf = b * NF + f;
            const float* p = pbase + f * 8;
            focal += p[0]; dnum += p[1]; dden += p[2];
            pYn += p[3]; pYd += p[4]; pXn += p[5]; pXd += p[6];
            tsum += ws[WS_TSUM + bf];
            ysum += ws[WS_YSUM + bf];
            xsum += ws[WS_XSUM + bf];
        }
        float cost_mask = focal / (float)DTOT;
        float cost_dice = -(2.f * dnum + 1.f) / (dden + tsum + 1.f);
        float coefY = (2.f * pYn + 1.f) / (pYd + ysum + 1.f);
        float coefX = (2.f * pXn + 1.f) / (pXd + xsum + 1.f);
        float cost_proj = -0.5f * (coefY + coefX);

        float wsum = 0.f, cls = 0.f, cb = 0.f, cg = 0.f;
        #pragma unroll
        for (int f = 0; f < NF; ++f) {
            float wv = (tvalid[b * NF + f] != 0) ? 1.f : 0.f;
            wsum += wv;
            float lg = logits[(b * NF + f) * NQ + q];
            float p = sigmoid_fast(lg);
            float negc = 0.75f * p * p * (-__logf(1.f - p + 1e-8f));
            float posc = 0.25f * (1.f - p) * (1.f - p) * (-__logf(p + 1e-8f));
            cls += (posc - negc) * wv;

            const float* bx = boxes + (size_t)((b * NF + f) * NQ + q) * 4;
            const float* tb = tbox + (b * NF + f) * 4;
            float cx = bx[0], cy = bx[1], bw = bx[2], bh = bx[3];
            float tcx = tb[0], tcy = tb[1], tbw = tb[2], tbh = tb[3];
            cb += fabsf(cx - tcx) + fabsf(cy - tcy) + fabsf(bw - tbw) + fabsf(bh - tbh);
            float sx1 = cx - 0.5f * bw, sy1 = cy - 0.5f * bh;
            float sx2 = cx + 0.5f * bw, sy2 = cy + 0.5f * bh;
            float tx1 = tcx - 0.5f * tbw, ty1 = tcy - 0.5f * tbh;
            float tx2 = tcx + 0.5f * tbw, ty2 = tcy + 0.5f * tbh;
            float a1 = (sx2 - sx1) * (sy2 - sy1), a2 = (tx2 - tx1) * (ty2 - ty1);
            float iw = fmaxf(fminf(sx2, tx2) - fmaxf(sx1, tx1), 0.f);
            float ih = fmaxf(fminf(sy2, ty2) - fmaxf(sy1, ty1), 0.f);
            float inter = iw * ih;
            float uni = a1 + a2 - inter;
            float iou = inter / uni;
            float cw = fmaxf(fmaxf(sx2, tx2) - fminf(sx1, tx1), 0.f);
            float chh = fmaxf(fmaxf(sy2, ty2) - fminf(sy1, ty1), 0.f);
            float areac = cw * chh;
            cg += -(iou - (areac - uni) / areac);
        }
        cls /= wsum;
        cb *= 0.125f;
        cg *= 0.125f;
        float val = cls + cb + cg + cost_mask + cost_dice + cost_proj;
        out[t] = val;
        sv[t] = val;
    }
    __syncthreads();

    int wid = t >> 6, lane = t & 63;
    if (wid < 2 && write_idx) {
        int b = wid;
        float best = INFINITY;
        int bi = 0x7fffffff;
        for (int q = lane; q < NQ; q += 64) {
            float v = sv[b * NQ + q];
            if (v < best) { best = v; bi = q; }
        }
        #pragma unroll
        for (int off = 32; off > 0; off >>= 1) {
            float ov = __shfl_down(best, off, 64);
            int oi = __shfl_down(bi, off, 64);
            if (ov < best || (ov == best && oi < bi)) { best = ov; bi = oi; }
        }
        if (lane == 0) {
            out[2 * NQ + b] = (float)bi;       // src_ind
            out[2 * NQ + 2 + b] = 0.f;         // tgt_ind
        }
    }
}

extern "C" void kernel_launch(void* const* d_in, const int* in_sizes, int n_in,
                              void* d_out, int out_size, void* d_ws, size_t ws_size,
                              hipStream_t stream) {
    const float* logits = (const float*)d_in[0];
    const float* boxes  = (const float*)d_in[1];
    const float* masks  = (const float*)d_in[2];
    const float* tmask  = (const float*)d_in[3];
    const float* tbox   = (const float*)d_in[4];
    const int*   tvalid = (const int*)d_in[5];
    const unsigned char* vpad = (const unsigned char*)d_in[6];
    float* out = (float*)d_out;
    float* ws  = (float*)d_ws;

    targets_kernel<<<NBF, NTT, 0, stream>>>(tmask, vpad, ws);
    partial_kernel<<<NBF * NPLB, NTP, 0, stream>>>(masks, ws, ws + WS_PART);
    int write_idx = (out_size >= 2 * NQ + 4) ? 1 : 0;
    combine_argmin_kernel<<<1, NTF, 0, stream>>>(logits, boxes, tbox, tvalid, ws, out,
                                                 write_idx);
}